// Round 4
// baseline (204.701 us; speedup 1.0000x reference)
//
#include <hip/hip_runtime.h>

// CRF loss, B=1024, T=512, K=32 — chunked associative scan.
//
// Linear domain: p_t^T = p_{t-1}^T * (E * D_t), E=exp(trans), D_t=diag(exp(emit_t)).
// Phase 1 (crf_chunk, 8192 waves = 1024 seq x 8 chunks, FULL occupancy):
//   per chunk compute M_c = prod_t (E*D_t) (identity if masked) with MFMA
//   16x16x32 bf16: M as A-operand (2 frags from LDS), E as constant B-frags in
//   registers. Column scale = exp(emit)*2^-5, one scalar per lane. C->A
//   transpose via LDS bf16 round-trip (single wave, in-order DS, no barrier).
//   Power-of-2 renorm every 8 steps; log-scale accumulated in S_c.
//   Each wave also computes its chunk's point+trans score (parallel).
// Phase 2 (crf_combine, 512 blocks): per sequence 8 serial matvecs p^T*M_c
//   (tiny), final logsumexp, minus scores.

#define K32 32
#define Tt  512
#define NCH 8
#define CHL 64

typedef float  float4v __attribute__((ext_vector_type(4)));
typedef short  short8v __attribute__((ext_vector_type(8)));

#define SWZX(x, m) __int_as_float(__builtin_amdgcn_ds_swizzle(__float_as_int(x), ((m) << 10) | 0x1F))
#define SWZ0(x)    __int_as_float(__builtin_amdgcn_ds_swizzle(__float_as_int(x), 0x0000))

__device__ inline unsigned short f2bf(float x) {
    unsigned u = __float_as_uint(x);
    unsigned r = (u + 0x7FFFu + ((u >> 16) & 1u)) >> 16;
    return (unsigned short)r;
}
__device__ inline float bf2f(unsigned short h) {
    return __uint_as_float(((unsigned)h) << 16);
}

// ---------------- Phase 1: per-chunk matrix product ----------------
__global__ __launch_bounds__(64) void crf_chunk(
    const int*   __restrict__ labels,
    const float* __restrict__ y_pred,
    const float* __restrict__ trans,
    const float* __restrict__ mask,
    unsigned*    __restrict__ wsM,    // [1024*8][512] dwords: bf16 row-major 32x32 (cols 2d,2d+1 per dword)
    float*       __restrict__ wsS,    // [1024*8] log-scale per chunk
    float*       __restrict__ wsSc)   // [1024*8] path-score per chunk
{
    __shared__ unsigned short shM[32 * 40];   // row stride 40 bf16 = 80 B (16B-aligned rows)

    const int lane = threadIdx.x;             // 0..63
    const int n    = lane & 15;               // MFMA col / A-row-in-tile
    const int q    = lane >> 4;               // MFMA quad
    const int seq  = blockIdx.x >> 3;
    const int c    = blockIdx.x & 7;

    const float* yp = y_pred + (size_t)seq * Tt * K32;
    const int*   lb = labels + (size_t)seq * Tt;
    const float* mk = mask   + (size_t)seq * Tt;

    // ---- chunk path score (fully parallel; 64 lanes <-> 64 timesteps) ----
    float sc;
    {
        const int t = c * CHL + lane;
        const int   lab0 = lb[t];
        const float mv0  = mk[t];
        sc = yp[t * K32 + lab0] * mv0;
        if (t < Tt - 1) {
            sc += trans[lab0 * K32 + lb[t + 1]] * (mv0 * mk[t + 1]);
        }
#pragma unroll
        for (int s = 1; s < 64; s <<= 1) sc += __shfl_xor(sc, s, 64);
    }

    // ---- constant E B-frags: B[k = q*8+j][col = 16J + n] ----
    short8v BE0, BE1;
#pragma unroll
    for (int jj = 0; jj < 8; ++jj) {
        BE0[jj] = (short)f2bf(__expf(trans[(q * 8 + jj) * K32 + n]));
        BE1[jj] = (short)f2bf(__expf(trans[(q * 8 + jj) * K32 + 16 + n]));
    }

    // ---- identity init ----
    for (int idx = lane; idx < 32 * 32; idx += 64) {
        const int r = idx >> 5, cc = idx & 31;
        shM[r * 40 + cc] = (r == cc) ? (unsigned short)0x3F80 : (unsigned short)0;
    }
    __syncthreads();

    const int t0 = (c == 0) ? 1 : c * CHL;
    const int t1 = c * CHL + CHL - 1;

    float Slog   = 0.0f;
    int   applied = 0;

    float ea0 = yp[t0 * K32 + n];
    float ea1 = yp[t0 * K32 + 16 + n];

    for (int t = t0; t <= t1; ++t) {
        const float y0 = ea0, y1 = ea1;
        if (t < t1) { ea0 = yp[(t + 1) * K32 + n]; ea1 = yp[(t + 1) * K32 + 16 + n]; }
        const float mv = mk[t];
        if (mv != 0.0f) {                         // wave-uniform branch
            // A-frags: M rows 16I+n, k = q*8..q*8+7 (row-major bf16, contiguous 16B)
            const short8v A0 = *(const short8v*)&shM[n * 40 + q * 8];
            const short8v A1 = *(const short8v*)&shM[(16 + n) * 40 + q * 8];

            float4v a00 = {0.f, 0.f, 0.f, 0.f}, a01 = {0.f, 0.f, 0.f, 0.f};
            float4v a10 = {0.f, 0.f, 0.f, 0.f}, a11 = {0.f, 0.f, 0.f, 0.f};
            a00 = __builtin_amdgcn_mfma_f32_16x16x32_bf16(A0, BE0, a00, 0, 0, 0);
            a01 = __builtin_amdgcn_mfma_f32_16x16x32_bf16(A0, BE1, a01, 0, 0, 0);
            a10 = __builtin_amdgcn_mfma_f32_16x16x32_bf16(A1, BE0, a10, 0, 0, 0);
            a11 = __builtin_amdgcn_mfma_f32_16x16x32_bf16(A1, BE1, a11, 0, 0, 0);

            const float s0 = __expf(y0) * 0.03125f;   // col scale incl. 2^-5
            const float s1 = __expf(y1) * 0.03125f;
#pragma unroll
            for (int r = 0; r < 4; ++r) {
                a00[r] *= s0; a10[r] *= s0;
                a01[r] *= s1; a11[r] *= s1;
            }

            if ((applied & 7) == 7) {             // power-of-2 renorm
                float mx = a00[0];
#pragma unroll
                for (int r = 0; r < 4; ++r) {
                    mx = fmaxf(mx, a00[r]); mx = fmaxf(mx, a01[r]);
                    mx = fmaxf(mx, a10[r]); mx = fmaxf(mx, a11[r]);
                }
#pragma unroll
                for (int s = 1; s < 64; s <<= 1) mx = fmaxf(mx, __shfl_xor(mx, s, 64));
                int ke;
                (void)frexpf(mx, &ke);
                const float rs = ldexpf(1.0f, -ke);
#pragma unroll
                for (int r = 0; r < 4; ++r) {
                    a00[r] *= rs; a01[r] *= rs; a10[r] *= rs; a11[r] *= rs;
                }
                Slog += (float)ke * 0.69314718f;
            }
            ++applied;

            // write back: C row = 16I + q*4 + r, col = 16J + n
#pragma unroll
            for (int r = 0; r < 4; ++r) {
                const int row0 = q * 4 + r;
                shM[row0 * 40 + n]              = f2bf(a00[r]);
                shM[row0 * 40 + 16 + n]         = f2bf(a01[r]);
                shM[(16 + row0) * 40 + n]       = f2bf(a10[r]);
                shM[(16 + row0) * 40 + 16 + n]  = f2bf(a11[r]);
            }
        }
    }

    __syncthreads();
    // dump M (bf16, 32x32, row-major, no pad) + scalars
    unsigned* md = wsM + (size_t)blockIdx.x * 512;
    const unsigned* shd = (const unsigned*)shM;   // dword view: row stride 20
    for (int idx = lane; idx < 512; idx += 64) {
        const int r = idx >> 4, d = idx & 15;
        md[idx] = shd[r * 20 + d];
    }
    if (lane == 0) {
        wsS[blockIdx.x]  = Slog + (float)applied * 3.46573590f;   // + applied*5*ln2
        wsSc[blockIdx.x] = sc;
    }
}

// ---------------- Phase 2: serial combine (8 matvecs/seq) ----------------
__global__ __launch_bounds__(64) void crf_combine(
    const float*    __restrict__ y_pred,
    const unsigned* __restrict__ wsM,
    const float*    __restrict__ wsS,
    const float*    __restrict__ wsSc,
    float*          __restrict__ out)
{
    __shared__ __align__(16) float sh_p[64];

    const int lane = threadIdx.x;
    const int half = lane >> 5;
    const int j    = lane & 31;
    const int seq  = blockIdx.x * 2 + half;

    const float* yp = y_pred + (size_t)seq * Tt * K32;

    const float a0 = yp[j];
    const float m0 = SWZ0(a0);
    float p = __expf(a0 - m0);
    float S = m0;
    float sc = 0.0f;
#pragma unroll
    for (int cc = 0; cc < NCH; ++cc) {
        S  += wsS[seq * NCH + cc];
        sc += wsSc[seq * NCH + cc];
    }

    const float4* e4 = (const float4*)&sh_p[half * K32];
    const int dsel = j >> 1;        // dword within row
    const int hsel = j & 1;         // hi/lo bf16

    for (int cc = 0; cc < NCH; ++cc) {
        const unsigned* M = wsM + (size_t)(seq * NCH + cc) * 512;
        sh_p[lane] = p;
        float acc = 0.0f;
        float cnorm = 0.0f;
#pragma unroll
        for (int ib = 0; ib < 8; ++ib) {
            const float4 pv = e4[ib];
            if (ib == 0) cnorm = pv.x;
            const unsigned d0 = M[(ib * 4 + 0) * 16 + dsel];
            const unsigned d1 = M[(ib * 4 + 1) * 16 + dsel];
            const unsigned d2 = M[(ib * 4 + 2) * 16 + dsel];
            const unsigned d3 = M[(ib * 4 + 3) * 16 + dsel];
            acc = fmaf(pv.x, bf2f(hsel ? (unsigned short)(d0 >> 16) : (unsigned short)d0), acc);
            acc = fmaf(pv.y, bf2f(hsel ? (unsigned short)(d1 >> 16) : (unsigned short)d1), acc);
            acc = fmaf(pv.z, bf2f(hsel ? (unsigned short)(d2 >> 16) : (unsigned short)d2), acc);
            acc = fmaf(pv.w, bf2f(hsel ? (unsigned short)(d3 >> 16) : (unsigned short)d3), acc);
        }
        const float r = 1.0f / cnorm;
        p = acc * r;
        S += __logf(cnorm);
    }

    float sp = p;
    sp += SWZX(sp, 1);
    sp += SWZX(sp, 2);
    sp += SWZX(sp, 4);
    sp += SWZX(sp, 8);
    sp += SWZX(sp, 16);

    if (j == 0) {
        out[seq] = S + __logf(sp) - sc;
    }
}

extern "C" void kernel_launch(void* const* d_in, const int* in_sizes, int n_in,
                              void* d_out, int out_size, void* d_ws, size_t ws_size,
                              hipStream_t stream) {
    const int*   labels = (const int*)  d_in[0];
    const float* y_pred = (const float*)d_in[1];
    const float* trans  = (const float*)d_in[2];
    const float* mask   = (const float*)d_in[3];
    float* out = (float*)d_out;

    // workspace carve: M (16 MB) | S (32 KB) | Sc (32 KB)
    unsigned* wsM = (unsigned*)d_ws;
    float* wsS  = (float*)((char*)d_ws + (size_t)1024 * NCH * 512 * 4);
    float* wsSc = wsS + 1024 * NCH;

    crf_chunk<<<1024 * NCH, 64, 0, stream>>>(labels, y_pred, trans, mask, wsM, wsS, wsSc);
    crf_combine<<<512, 64, 0, stream>>>(y_pred, wsM, wsS, wsSc, out);
}

// Round 5
// 173.311 us; speedup vs baseline: 1.1811x; 1.1811x over previous
//
#include <hip/hip_runtime.h>

// CRF loss, B=1024, T=512, K=32 — chunked associative scan, transposed form.
//
// Linear domain: p_t^T = p_{t-1}^T (E D_t).  We track N = M^T per chunk:
//   N <- (D_t E^T) N,  so A-operand = D_t E^T (constant E^T f32 in regs,
// scaled by one exp(emit_m) scalar per row-half per lane, truncation-packed
// to bf16 via v_perm_b32), B-operand = N from LDS (conflict-free b128 reads),
// C written back as contiguous column segments (4 x ds_write_b64, ~2-way max
// aliasing = free). Power-of-2 renorm every 8 steps. Dump emits M^T row-major
// so the combine kernel reads rows contiguously from LDS.

#define K32 32
#define Tt  512
#define NCH 8
#define CHL 64

typedef float  float4v __attribute__((ext_vector_type(4)));
typedef short  short8v __attribute__((ext_vector_type(8)));

#define SWZX(x, m) __int_as_float(__builtin_amdgcn_ds_swizzle(__float_as_int(x), ((m) << 10) | 0x1F))
#define SWZ0(x)    __int_as_float(__builtin_amdgcn_ds_swizzle(__float_as_int(x), 0x0000))

__device__ inline float bf2f(unsigned h) {
    return __uint_as_float(h << 16);
}
// pack two f32 -> bf16x2 dword by truncation: low16 = hi16(lo), high16 = hi16(hi)
__device__ inline unsigned pack_trunc(float hi, float lo) {
    return __builtin_amdgcn_perm(__float_as_uint(hi), __float_as_uint(lo), 0x07060302u);
}

union F8 { unsigned u[4]; short8v v; };

// ---------------- Phase 1: per-chunk matrix product (transposed) ----------------
__global__ __launch_bounds__(64) void crf_chunk(
    const int*   __restrict__ labels,
    const float* __restrict__ y_pred,
    const float* __restrict__ trans,
    const float* __restrict__ mask,
    unsigned*    __restrict__ wsMT,   // [1024*8][512] dwords: M^T row-major bf16x2
    float*       __restrict__ wsS,    // [1024*8] log-scale per chunk
    float*       __restrict__ wsSc)   // [1024*8] path-score per chunk
{
    __shared__ unsigned short shN[32 * 40];   // shN[c*40 + k] = N[k][c]; stride 40 bf16

    const int lane = threadIdx.x;             // 0..63
    const int n    = lane & 15;
    const int q    = lane >> 4;
    const int seq  = blockIdx.x >> 3;
    const int c    = blockIdx.x & 7;

    const float* yp = y_pred + (size_t)seq * Tt * K32;
    const int*   lb = labels + (size_t)seq * Tt;
    const float* mk = mask   + (size_t)seq * Tt;

    // ---- chunk path score (parallel: 64 lanes <-> 64 timesteps) ----
    float sc;
    {
        const int t = c * CHL + lane;
        const int   lab0 = lb[t];
        const float mv0  = mk[t];
        sc = yp[t * K32 + lab0] * mv0;
        if (t < Tt - 1) {
            sc += trans[lab0 * K32 + lb[t + 1]] * (mv0 * mk[t + 1]);
        }
#pragma unroll
        for (int s = 1; s < 64; s <<= 1) sc += __shfl_xor(sc, s, 64);
    }

    // ---- constant A base: Ef_I[j] = E[k=q*8+j][m=16I+n] * 2^-5  (f32) ----
    float Ef0[8], Ef1[8];
#pragma unroll
    for (int jj = 0; jj < 8; ++jj) {
        Ef0[jj] = __expf(trans[(q * 8 + jj) * K32 + n])      * 0.03125f;
        Ef1[jj] = __expf(trans[(q * 8 + jj) * K32 + 16 + n]) * 0.03125f;
    }

    // ---- N = I ----
    for (int idx = lane; idx < 32 * 32; idx += 64) {
        const int r = idx >> 5, k = idx & 31;
        shN[r * 40 + k] = (r == k) ? (unsigned short)0x3F80 : (unsigned short)0;
    }
    __syncthreads();

    const int t0 = (c == 0) ? 1 : c * CHL;
    const int t1 = c * CHL + CHL - 1;

    float Slog    = 0.0f;
    int   applied = 0;

    float ea0 = yp[t0 * K32 + n];
    float ea1 = yp[t0 * K32 + 16 + n];

    for (int t = t0; t <= t1; ++t) {
        const float y0 = ea0, y1 = ea1;
        if (t < t1) { ea0 = yp[(t + 1) * K32 + n]; ea1 = yp[(t + 1) * K32 + 16 + n]; }
        const float mv = mk[t];
        if (mv != 0.0f) {                         // wave-uniform
            const float s0 = __expf(y0);
            const float s1 = __expf(y1);
            F8 A0, A1;
#pragma unroll
            for (int h = 0; h < 4; ++h) {
                A0.u[h] = pack_trunc(s0 * Ef0[2 * h + 1], s0 * Ef0[2 * h]);
                A1.u[h] = pack_trunc(s1 * Ef1[2 * h + 1], s1 * Ef1[2 * h]);
            }
            const short8v B0 = *(const short8v*)&shN[n * 40 + q * 8];
            const short8v B1 = *(const short8v*)&shN[(16 + n) * 40 + q * 8];

            float4v c00 = {0.f, 0.f, 0.f, 0.f}, c01 = {0.f, 0.f, 0.f, 0.f};
            float4v c10 = {0.f, 0.f, 0.f, 0.f}, c11 = {0.f, 0.f, 0.f, 0.f};
            c00 = __builtin_amdgcn_mfma_f32_16x16x32_bf16(A0.v, B0, c00, 0, 0, 0);
            c01 = __builtin_amdgcn_mfma_f32_16x16x32_bf16(A0.v, B1, c01, 0, 0, 0);
            c10 = __builtin_amdgcn_mfma_f32_16x16x32_bf16(A1.v, B0, c10, 0, 0, 0);
            c11 = __builtin_amdgcn_mfma_f32_16x16x32_bf16(A1.v, B1, c11, 0, 0, 0);

            if ((applied & 7) == 7) {             // power-of-2 renorm
                float mx = c00[0];
#pragma unroll
                for (int r = 0; r < 4; ++r) {
                    mx = fmaxf(mx, c00[r]); mx = fmaxf(mx, c01[r]);
                    mx = fmaxf(mx, c10[r]); mx = fmaxf(mx, c11[r]);
                }
#pragma unroll
                for (int s = 1; s < 64; s <<= 1) mx = fmaxf(mx, __shfl_xor(mx, s, 64));
                int ke;
                (void)frexpf(mx, &ke);
                const float rs = ldexpf(1.0f, -ke);
#pragma unroll
                for (int r = 0; r < 4; ++r) {
                    c00[r] *= rs; c01[r] *= rs; c10[r] *= rs; c11[r] *= rs;
                }
                Slog += (float)ke * 0.69314718f;
            }
            ++applied;

            // write back N_new: col = 16J+n, rows 16I + q*4 .. +3 (contiguous b64)
            uint2 w;
            w.x = pack_trunc(c00[1], c00[0]); w.y = pack_trunc(c00[3], c00[2]);
            *(uint2*)&shN[n * 40 + q * 4] = w;                       // I=0,J=0
            w.x = pack_trunc(c01[1], c01[0]); w.y = pack_trunc(c01[3], c01[2]);
            *(uint2*)&shN[(16 + n) * 40 + q * 4] = w;                // I=0,J=1
            w.x = pack_trunc(c10[1], c10[0]); w.y = pack_trunc(c10[3], c10[2]);
            *(uint2*)&shN[n * 40 + 16 + q * 4] = w;                  // I=1,J=0
            w.x = pack_trunc(c11[1], c11[0]); w.y = pack_trunc(c11[3], c11[2]);
            *(uint2*)&shN[(16 + n) * 40 + 16 + q * 4] = w;           // I=1,J=1
        }
    }

    __syncthreads();
    // dump M^T row-major: wsMT[bid][k*16 + d] = bf16x2( M^T[k][2d], M^T[k][2d+1] )
    // M^T[k][c] = N[k][c] = shN[c*40 + k]
    unsigned* md = wsMT + (size_t)blockIdx.x * 512;
    for (int idx = lane; idx < 512; idx += 64) {
        const int k = idx >> 4, d = idx & 15;
        const unsigned lo = shN[(2 * d) * 40 + k];
        const unsigned hi = shN[(2 * d + 1) * 40 + k];
        md[idx] = lo | (hi << 16);
    }
    if (lane == 0) {
        wsS[blockIdx.x]  = Slog + (float)applied * 3.46573590f;   // + applied*5*ln2
        wsSc[blockIdx.x] = sc;
    }
}

// ---------------- Phase 2: serial combine (LDS-staged) ----------------
__global__ __launch_bounds__(64) void crf_combine(
    const float*    __restrict__ y_pred,
    const unsigned* __restrict__ wsMT,
    const float*    __restrict__ wsS,
    const float*    __restrict__ wsSc,
    float*          __restrict__ out)
{
    __shared__ unsigned shA[16 * 32 * 20];        // 16 matrices, row stride 20 dwords (40 KB)
    __shared__ __align__(16) float sh_p[64];

    const int lane = threadIdx.x;
    const int half = lane >> 5;
    const int j    = lane & 31;
    const int seq  = blockIdx.x * 2 + half;

    const float* yp = y_pred + (size_t)seq * Tt * K32;

    // stage 16 matrices (2 seqs x 8 chunks), coalesced b128
    const uint4* src = (const uint4*)(wsMT + (size_t)blockIdx.x * 2 * NCH * 512);
    for (int g = lane; g < 2048; g += 64) {
        const uint4 v = src[g];
        const int fd  = g << 2;
        const int scm = fd >> 9;
        const int rem = fd & 511;
        const int k   = rem >> 4;
        const int d   = rem & 15;
        *(uint4*)&shA[scm * 640 + k * 20 + d] = v;
    }
    __syncthreads();

    const float a0 = yp[j];
    const float m0 = SWZ0(a0);
    float p = __expf(a0 - m0);
    float S = m0;
    float scs = 0.0f;
#pragma unroll
    for (int cc = 0; cc < NCH; ++cc) {
        S   += wsS[seq * NCH + cc];
        scs += wsSc[seq * NCH + cc];
    }

    const float4* e4 = (const float4*)&sh_p[half * K32];

    for (int cc = 0; cc < NCH; ++cc) {
        sh_p[lane] = p;
        const unsigned* row = &shA[(half * NCH + cc) * 640 + j * 20];  // M^T row j
        float acc = 0.0f, cn = 0.0f;
#pragma unroll
        for (int ib = 0; ib < 8; ++ib) {
            const float4 pv = e4[ib];
            if (ib == 0) cn = pv.x;
            const unsigned d0 = row[2 * ib];
            const unsigned d1 = row[2 * ib + 1];
            acc = fmaf(pv.x, bf2f(d0 & 0xFFFFu), acc);
            acc = fmaf(pv.y, bf2f(d0 >> 16),     acc);
            acc = fmaf(pv.z, bf2f(d1 & 0xFFFFu), acc);
            acc = fmaf(pv.w, bf2f(d1 >> 16),     acc);
        }
        const float r = 1.0f / cn;
        p = acc * r;
        S += __logf(cn);
    }

    float sp = p;
    sp += SWZX(sp, 1);
    sp += SWZX(sp, 2);
    sp += SWZX(sp, 4);
    sp += SWZX(sp, 8);
    sp += SWZX(sp, 16);

    if (j == 0) {
        out[seq] = S + __logf(sp) - scs;
    }
}

extern "C" void kernel_launch(void* const* d_in, const int* in_sizes, int n_in,
                              void* d_out, int out_size, void* d_ws, size_t ws_size,
                              hipStream_t stream) {
    const int*   labels = (const int*)  d_in[0];
    const float* y_pred = (const float*)d_in[1];
    const float* trans  = (const float*)d_in[2];
    const float* mask   = (const float*)d_in[3];
    float* out = (float*)d_out;

    // workspace carve: M^T (16 MB) | S (32 KB) | Sc (32 KB)
    unsigned* wsMT = (unsigned*)d_ws;
    float* wsS  = (float*)((char*)d_ws + (size_t)1024 * NCH * 512 * 4);
    float* wsSc = wsS + 1024 * NCH;

    crf_chunk<<<1024 * NCH, 64, 0, stream>>>(labels, y_pred, trans, mask, wsMT, wsS, wsSc);
    crf_combine<<<512, 64, 0, stream>>>(y_pred, wsMT, wsS, wsSc, out);
}